// Round 11
// baseline (54.246 us; speedup 1.0000x reference)
//
#include <hip/hip_runtime.h>
#include <hip/hip_bf16.h>

// Problem constants
#define Bn   4
#define Cn   64
#define Hn   96
#define Wn   96
#define Gn   4
#define CGn  16      // Cn / Gn
#define KKn  9
#define NOFF 18      // 2*K*K offset channels
#define HWn  (Hn*Wn) // 9216
#define PW   98      // padded width/height (1-px halo)
#define XH_PIX (PW*PW)   // 9604 pixels per batch

// ws layout (floats)
#define OFF_BASE  0                        // B*HW*18 pos-major offsets (663552 fl)
#define AWF_BASE  (Bn*HWn*NOFF)            // offconv A-frags: 18432 bf16 = 9216 fl
#define WMF_BASE  (AWF_BASE + 9216)        // deform A-frags: 10240 bf16 = 5120 fl
#define XH_BASE   (WMF_BASE + 5120)        // xh[b][98][98][64] bf16 = 2458624 sh
#define XH_BYTES  (Bn * XH_PIX * Cn * 2)   // 4917248 B

typedef __attribute__((ext_vector_type(8))) short short8v;   // 8 bf16 = 4 VGPR
typedef __attribute__((ext_vector_type(4))) float f32x4;
typedef __attribute__((ext_vector_type(2))) float f32x2;
typedef __attribute__((ext_vector_type(4))) unsigned int uint4v;
typedef unsigned short ushort_t;

__device__ inline short f2bs(float v) {
    __hip_bfloat16 h = __float2bfloat16(v);
    return *reinterpret_cast<short*>(&h);
}
__device__ inline unsigned pack2bf(float lo, float hi) {
    return (unsigned)(ushort_t)f2bs(lo) | ((unsigned)(ushort_t)f2bs(hi) << 16);
}

// ---------------------------------------------------------------------------
// Kernel 0 (fused). Blocks [0,576): transpose x NCHW fp32 -> padded NHWC bf16
// xh[b][py][px][64] (halo pre-zeroed by hipMemsetAsync). Blocks >= 576: pack
//  (a) offconv A-frags awf: kappa slot u=s*4+q -> k=u%9, co=u/9, ci=co*8+j;
//      idx = ((s*2+t)*16+row)*4*8 + q*8 + j ; o = t*16+row (o>=18 -> 0)
//  (b) deform A-frags wmf (kappa = ch + 16*tap), as before.
// ---------------------------------------------------------------------------
#define NTRB (Bn * (HWn / 64))   // 576 transpose blocks
__global__ __launch_bounds__(256) void prep_all(
    const float* __restrict__ x, const float* __restrict__ w_off,
    const float* __restrict__ w_def, float* __restrict__ ws)
{
    __shared__ float t[64][65];
    if (blockIdx.x < NTRB) {
        const int nb = HWn / 64;               // 144
        const int b  = blockIdx.x / nb;
        const int p0 = (blockIdx.x % nb) * 64;
        ushort_t* xh = (ushort_t*)(ws + XH_BASE);
        for (int i = threadIdx.x; i < 64 * 64; i += 256) {
            const int c = i >> 6, l = i & 63;
            t[c][l] = x[(b * Cn + c) * HWn + p0 + l];
        }
        __syncthreads();
        for (int i = threadIdx.x; i < 64 * 32; i += 256) {
            const int l = i >> 5, cp = i & 31;      // cp = channel pair
            const int pos = p0 + l;
            const int ho = pos / Wn, wo = pos % Wn;
            const unsigned pk = pack2bf(t[cp * 2][l], t[cp * 2 + 1][l]);
            *(unsigned*)(xh + ((size_t)b * XH_PIX + (ho + 1) * PW + wo + 1) * Cn
                             + cp * 2) = pk;
        }
        return;
    }
    const int i = (blockIdx.x - NTRB) * 256 + threadIdx.x;
    const int NA = 18 * 2 * 16 * 4 * 8;    // 18432 offconv A-frag elems
    const int NW = Gn * 5 * CGn * 4 * 8;   // 10240 deform A-frag elems
    if (i < NA) {
        const int jj  = i & 7;
        const int q   = (i >> 3) & 3;
        const int row = (i >> 5) & 15;
        const int tt  = (i >> 9) & 1;
        const int s   = i >> 10;           // 0..17
        const int u   = s * 4 + q;
        const int k   = u % 9, co = u / 9;
        const int ci  = co * 8 + jj;
        const int o   = tt * 16 + row;
        const float v = (o < NOFF) ? w_off[(o * Cn + ci) * KKn + k] : 0.f;
        ((__hip_bfloat16*)(ws + AWF_BASE))[i] = __float2bfloat16(v);
    } else if (i < NA + NW) {
        const int j  = i - NA;
        const int jj = j & 7;
        const int q  = (j >> 3) & 3;
        const int d  = (j >> 5) & 15;
        const int kp = (j >> 9) % 5;
        const int g  = j / 2560;
        const int c  = (q & 1) * 8 + jj;
        const int k  = 2 * kp + (q >> 1);
        const float v = (k < KKn) ? w_def[((g * CGn + d) * CGn + c) * KKn + k] : 0.f;
        ((__hip_bfloat16*)(ws + WMF_BASE))[j] = __float2bfloat16(v);
    }
}

// ---------------------------------------------------------------------------
// Kernel 1: offset conv as MFMA GEMM: out[o][pos] (o<18, K = 64ci x 9tap).
// Wave = 16 pos. Lane (pr=l&15, q=l>>4). 18 kappa-steps; per step: one B-load
// (dwordx4 = 8 bf16 ch of shifted pixel, halo -> no bounds checks) + two
// A-frag loads; 2 MFMAs. asm pipeline depth 6, counted vmcnt.
// ---------------------------------------------------------------------------
__global__ __launch_bounds__(256) void offset_conv_v4(
    const float* __restrict__ ws, const float* __restrict__ bias,
    float* __restrict__ offs)
{
    // grid = 576 = 8 * 72 : XCD-swizzled
    const int bid = (blockIdx.x & 7) * 72 + (blockIdx.x >> 3);
    const int b = bid / 144;
    const int r = bid % 144;
    const int wave = threadIdx.x >> 6;
    const int lane = threadIdx.x & 63;
    const int pr = lane & 15, q = lane >> 4;
    const int pos0 = r * 64 + wave * 16;
    const int pos = pos0 + pr;
    const int ho = pos / Wn, wo = pos % Wn;
    const unsigned basep = (unsigned)(ho * PW + wo) * 128u;  // halo: +ki rows, +kj cols

    const ushort_t* xhb = (const ushort_t*)(ws + XH_BASE) + (size_t)b * XH_PIX * Cn;
    const ushort_t* awf = (const ushort_t*)(ws + AWF_BASE);
    const unsigned pa = (unsigned)(pr * 64 + q * 16);

    f32x4 bi4 = *(const f32x4*)(bias + q * 4);
    f32x2 bi2 = *(const f32x2*)(bias + 16);
    asm volatile("" : "+v"(bi4));
    asm volatile("" : "+v"(bi2));
    asm volatile("s_waitcnt vmcnt(0)" ::: "memory");
    __builtin_amdgcn_sched_barrier(0);

    short8v bfr[6], a0f[6], a1f[6];
    int kk = q, co = 0;          // invariant: u = s*4+q = 9*co + kk
    f32x4 acc0 = {0.f,0.f,0.f,0.f}, acc1 = {0.f,0.f,0.f,0.f};

#define OISSUE(S) { \
    const int ki = kk / 3, kj = kk % 3; \
    const unsigned voff = basep + (unsigned)(ki * PW + kj) * 128u + (unsigned)co * 16u; \
    asm volatile("global_load_dwordx4 %0, %1, %2" : "=v"(bfr[(S)%6]) : "v"(voff), "s"(xhb)); \
    const unsigned aoff = pa + (unsigned)(S) * 2048u; \
    asm volatile("global_load_dwordx4 %0, %1, %2" : "=v"(a0f[(S)%6]) : "v"(aoff), "s"(awf)); \
    asm volatile("global_load_dwordx4 %0, %1, %2" : "=v"(a1f[(S)%6]) : "v"(aoff + 1024u), "s"(awf)); \
    kk += 4; const int cy_ = (kk >= 9) ? 1 : 0; co += cy_; kk -= cy_ * 9; }

#define OCONS(S, N) { \
    asm volatile("s_waitcnt vmcnt(" #N ")" ::: "memory"); \
    __builtin_amdgcn_sched_barrier(0); \
    acc0 = __builtin_amdgcn_mfma_f32_16x16x32_bf16(a0f[(S)%6], bfr[(S)%6], acc0, 0, 0, 0); \
    acc1 = __builtin_amdgcn_mfma_f32_16x16x32_bf16(a1f[(S)%6], bfr[(S)%6], acc1, 0, 0, 0); }

    OISSUE(0) OISSUE(1) OISSUE(2) OISSUE(3) OISSUE(4) OISSUE(5)
    OCONS(0, 15) OISSUE(6)
    OCONS(1, 15) OISSUE(7)
    OCONS(2, 15) OISSUE(8)
    OCONS(3, 15) OISSUE(9)
    OCONS(4, 15) OISSUE(10)
    OCONS(5, 15) OISSUE(11)
    OCONS(6, 15) OISSUE(12)
    OCONS(7, 15) OISSUE(13)
    OCONS(8, 15) OISSUE(14)
    OCONS(9, 15) OISSUE(15)
    OCONS(10, 15) OISSUE(16)
    OCONS(11, 15) OISSUE(17)
    OCONS(12, 15)
    OCONS(13, 12)
    OCONS(14, 9)
    OCONS(15, 6)
    OCONS(16, 3)
    OCONS(17, 0)
#undef OISSUE
#undef OCONS

    // D: col = pr = pos-sub, row = q*4 + reg = o. Store o-runs as float2 pairs.
    float* dst = offs + (size_t)(b * HWn + pos0 + pr) * NOFF + q * 4;
    f32x2 s01; s01.x = acc0[0] + bi4.x; s01.y = acc0[1] + bi4.y;
    f32x2 s23; s23.x = acc0[2] + bi4.z; s23.y = acc0[3] + bi4.w;
    *(f32x2*)dst = s01;
    *(f32x2*)(dst + 2) = s23;
    if (q == 0) {
        f32x2 s67; s67.x = acc1[0] + bi2.x; s67.y = acc1[1] + bi2.y;
        *(f32x2*)(offs + (size_t)(b * HWn + pos0 + pr) * NOFF + 16) = s67;
    }
}

// ---------------------------------------------------------------------------
// Kernel 2: deformable conv via MFMA, kappa = ch + 16*tap, on padded xh.
// Wave = 16 pos. Lane (pr, q): half=q&1 channel octet, tp=q>>1 tap parity.
// 18 gather instrs/wave, 3-pair pipeline, counted vmcnt(8/8/8/4/0).
// ---------------------------------------------------------------------------
#define GLOAD4(dst, off_) \
    asm volatile("global_load_dwordx4 %0, %1, %2" \
                 : "=v"(dst) : "v"(off_), "s"(xhb))

__global__ __launch_bounds__(256) void deform_v10(
    const float* __restrict__ ws, float* __restrict__ out)
{
    const float* __restrict__ off2 = ws + OFF_BASE;
    const short8v* __restrict__ wmf = (const short8v*)(ws + WMF_BASE);

    // grid = 2304 = 8 * 288: XCD-swizzled
    const int bid = (blockIdx.x & 7) * 288 + (blockIdx.x >> 3);
    const int nbb = HWn / 64;              // 144 blocks per (b,g)
    const int bg  = bid / nbb;
    const int g   = bg & (Gn - 1);
    const int b   = bg >> 2;
    const int wave = threadIdx.x >> 6;
    const int lane = threadIdx.x & 63;
    const int pr   = lane & 15;
    const int q    = lane >> 4;
    const int half = q & 1;
    const int tp   = q >> 1;
    const int pos0 = (bid % nbb) * 64 + wave * 16;
    const int pos  = pos0 + pr;
    const int ho = pos / Wn, wo = pos % Wn;

    const f32x2* op2 = (const f32x2*)(off2 + (size_t)(b * HWn + pos) * NOFF);
    f32x2 o2[5];
    #pragma unroll
    for (int kp = 0; kp < 5; kp++) {
        int kq = 2 * kp + tp; if (kq > 8) kq = 8;   // tap9 -> dummy (cwt zeroed)
        o2[kp] = op2[kq];
    }
    short8v a[5];
    #pragma unroll
    for (int kp = 0; kp < 5; kp++)
        a[kp] = wmf[((g * 5 + kp) * CGn + pr) * 4 + q];

    const ushort_t* xhb = (const ushort_t*)(ws + XH_BASE) + (size_t)b * XH_PIX * Cn;
    const unsigned choff = (unsigned)(g * 32 + half * 16);

    #pragma unroll
    for (int kp = 0; kp < 5; kp++) {
        asm volatile("" : "+v"(o2[kp]));
        asm volatile("" : "+v"(a[kp]));
    }
    asm volatile("s_waitcnt vmcnt(0)" ::: "memory");
    __builtin_amdgcn_sched_barrier(0);

    float cwt[5][4];
    f32x4 dat[5][4];

#define PAIRSETUP(KP)                                                      \
  {                                                                        \
    const int k  = 2 * (KP) + tp;                                          \
    const int ki = k / 3, kj = k - 3 * ki;                                 \
    const float m = (k <= 8) ? 1.f : 0.f;                                  \
    const float ysf = (float)(ho - 1 + ki) + o2[KP].x;                     \
    const float xsf = (float)(wo - 1 + kj) + o2[KP].y;                     \
    const float y0f = floorf(ysf), x0f = floorf(xsf);                      \
    const int   y0  = (int)y0f,    x0  = (int)x0f;                         \
    const float wy1 = ysf - y0f, wx1 = xsf - x0f;                          \
    const float wy0 = 1.f - wy1, wx0 = 1.f - wx1;                          \
    const bool vy0 = (y0 >= 0)  && (y0 < Hn);                              \
    const bool vy1 = (y0 >= -1) && (y0 < Hn - 1);                          \
    const bool vx0 = (x0 >= 0)  && (x0 < Wn);                              \
    const bool vx1 = (x0 >= -1) && (x0 < Wn - 1);                          \
    const int cy0 = min(max(y0,     0), Hn - 1);                           \
    const int cy1 = min(max(y0 + 1, 0), Hn - 1);                           \
    const int cx0 = min(max(x0,     0), Wn - 1);                           \
    const int cx1 = min(max(x0 + 1, 0), Wn - 1);                           \
    cwt[KP][0] = m * wy0 * wx0 * ((vy0 && vx0) ? 1.f : 0.f);               \
    cwt[KP][1] = m * wy0 * wx1 * ((vy0 && vx1) ? 1.f : 0.f);               \
    cwt[KP][2] = m * wy1 * wx0 * ((vy1 && vx0) ? 1.f : 0.f);               \
    cwt[KP][3] = m * wy1 * wx1 * ((vy1 && vx1) ? 1.f : 0.f);               \
    const unsigned v00 = (unsigned)((cy0 + 1) * PW + cx0 + 1) * 128u + choff; \
    const unsigned v01 = (unsigned)((cy0 + 1) * PW + cx1 + 1) * 128u + choff; \
    const unsigned v10 = (unsigned)((cy1 + 1) * PW + cx0 + 1) * 128u + choff; \
    const unsigned v11 = (unsigned)((cy1 + 1) * PW + cx1 + 1) * 128u + choff; \
    GLOAD4(dat[KP][0], v00);                                               \
    GLOAD4(dat[KP][1], v01);                                               \
    GLOAD4(dat[KP][2], v10);                                               \
    GLOAD4(dat[KP][3], v11);                                               \
  }

    PAIRSETUP(0); PAIRSETUP(1); PAIRSETUP(2);

    f32x4 acc = {0.f, 0.f, 0.f, 0.f};

    #pragma unroll
    for (int kp = 0; kp < 5; kp++) {
        if (kp <= 2)      asm volatile("s_waitcnt vmcnt(8)" ::: "memory");
        else if (kp == 3) asm volatile("s_waitcnt vmcnt(4)" ::: "memory");
        else              asm volatile("s_waitcnt vmcnt(0)" ::: "memory");
        __builtin_amdgcn_sched_barrier(0);

        float s[8] = {0.f,0.f,0.f,0.f,0.f,0.f,0.f,0.f};
        #pragma unroll
        for (int c4 = 0; c4 < 4; c4++) {
            const float w = cwt[kp][c4];
            const uint4v u = *reinterpret_cast<const uint4v*>(&dat[kp][c4]);
            #pragma unroll
            for (int w2 = 0; w2 < 4; w2++) {
                unsigned lo = u[w2] << 16;
                unsigned hi = u[w2] & 0xffff0000u;
                s[2*w2]   += w * *reinterpret_cast<float*>(&lo);
                s[2*w2+1] += w * *reinterpret_cast<float*>(&hi);
            }
        }
        short8v fr;
        #pragma unroll
        for (int j = 0; j < 8; j++) fr[j] = f2bs(s[j]);
        acc = __builtin_amdgcn_mfma_f32_16x16x32_bf16(a[kp], fr, acc, 0, 0, 0);

        if (kp == 0) PAIRSETUP(3);
        if (kp == 1) PAIRSETUP(4);
    }

    float* op = out + (size_t)(b * Cn + g * CGn) * HWn + pos0;
    #pragma unroll
    for (int r = 0; r < 4; r++)
        op[(q * 4 + r) * HWn + pr] = acc[r];
}

// ---------------------------------------------------------------------------
extern "C" void kernel_launch(void* const* d_in, const int* in_sizes, int n_in,
                              void* d_out, int out_size, void* d_ws, size_t ws_size,
                              hipStream_t stream) {
    const float* x     = (const float*)d_in[0];
    const float* w_off = (const float*)d_in[1];
    const float* b_off = (const float*)d_in[2];
    const float* w_def = (const float*)d_in[3];
    float* out = (float*)d_out;
    float* ws  = (float*)d_ws;

    // zero the padded image (halo must be 0; interior overwritten by prep)
    (void)hipMemsetAsync((char*)d_ws + (size_t)XH_BASE * 4, 0, XH_BYTES, stream);

    const int n_pack = 18432 + 10240;                 // 28672 = 112 * 256
    const int nblk = NTRB + n_pack / 256;             // 576 + 112
    prep_all<<<nblk, 256, 0, stream>>>(x, w_off, w_def, ws);

    offset_conv_v4<<<576, 256, 0, stream>>>(ws, b_off, ws + OFF_BASE);

    deform_v10<<<Bn * Gn * (HWn / 64), 256, 0, stream>>>(ws, out);
}

// Round 14
// 50.394 us; speedup vs baseline: 1.0764x; 1.0764x over previous
//
#include <hip/hip_runtime.h>
#include <hip/hip_bf16.h>

// Problem constants
#define Bn   4
#define Cn   64
#define Hn   96
#define Wn   96
#define Gn   4
#define CGn  16      // Cn / Gn
#define KKn  9
#define NOFF 18      // 2*K*K offset channels
#define HWn  (Hn*Wn) // 9216
#define PW   98      // padded width/height (1-px halo)
#define XH_PIX (PW*PW)   // 9604 pixels per batch

// ws layout (floats)
#define OFF_BASE  0                        // B*HW*18 pos-major offsets (663552 fl)
#define AWF_BASE  (Bn*HWn*NOFF)            // offconv A-frags: 18432 bf16 = 9216 fl
#define WMF_BASE  (AWF_BASE + 9216)        // deform A-frags: 10240 bf16 = 5120 fl
#define XH_BASE   (WMF_BASE + 5120)        // xh[b][98][98][64] bf16 = 2458624 sh

typedef __attribute__((ext_vector_type(8))) short short8v;   // 8 bf16 = 4 VGPR
typedef __attribute__((ext_vector_type(4))) float f32x4;
typedef __attribute__((ext_vector_type(2))) float f32x2;
typedef __attribute__((ext_vector_type(4))) unsigned int uint4v;
typedef unsigned short ushort_t;

__device__ inline short f2bs(float v) {
    __hip_bfloat16 h = __float2bfloat16(v);
    return *reinterpret_cast<short*>(&h);
}
__device__ inline unsigned pack2bf(float lo, float hi) {
    return (unsigned)(ushort_t)f2bs(lo) | ((unsigned)(ushort_t)f2bs(hi) << 16);
}

// ---------------------------------------------------------------------------
// Kernel 0 (fused). Blocks [0,576): transpose x NCHW fp32 -> padded NHWC bf16
// xh[b][py][px][64]. Blocks [576,688): pack offconv + deform A-frags.
// Blocks [688,695): zero the 1-px halo (replaces hipMemsetAsync).
// ---------------------------------------------------------------------------
#define NTRB (Bn * (HWn / 64))   // 576 transpose blocks
__global__ __launch_bounds__(256) void prep_all(
    const float* __restrict__ x, const float* __restrict__ w_off,
    const float* __restrict__ w_def, float* __restrict__ ws)
{
    __shared__ float t[64][65];
    if (blockIdx.x < NTRB) {
        const int nb = HWn / 64;               // 144
        const int b  = blockIdx.x / nb;
        const int p0 = (blockIdx.x % nb) * 64;
        ushort_t* xh = (ushort_t*)(ws + XH_BASE);
        for (int i = threadIdx.x; i < 64 * 64; i += 256) {
            const int c = i >> 6, l = i & 63;
            t[c][l] = x[(b * Cn + c) * HWn + p0 + l];
        }
        __syncthreads();
        for (int i = threadIdx.x; i < 64 * 32; i += 256) {
            const int l = i >> 5, cp = i & 31;      // cp = channel pair
            const int pos = p0 + l;
            const int ho = pos / Wn, wo = pos % Wn;
            const unsigned pk = pack2bf(t[cp * 2][l], t[cp * 2 + 1][l]);
            *(unsigned*)(xh + ((size_t)b * XH_PIX + (ho + 1) * PW + wo + 1) * Cn
                             + cp * 2) = pk;
        }
        return;
    }
    const int i = (blockIdx.x - NTRB) * 256 + threadIdx.x;
    const int NA = 18 * 2 * 16 * 4 * 8;    // 18432 offconv A-frag elems
    const int NW = Gn * 5 * CGn * 4 * 8;   // 10240 deform A-frag elems
    if (i < NA) {
        const int jj  = i & 7;
        const int q   = (i >> 3) & 3;
        const int row = (i >> 5) & 15;
        const int tt  = (i >> 9) & 1;
        const int s   = i >> 10;           // 0..17
        const int u   = s * 4 + q;
        const int k   = u % 9, co = u / 9;
        const int ci  = co * 8 + jj;
        const int o   = tt * 16 + row;
        const float v = (o < NOFF) ? w_off[(o * Cn + ci) * KKn + k] : 0.f;
        ((__hip_bfloat16*)(ws + AWF_BASE))[i] = __float2bfloat16(v);
    } else if (i < NA + NW) {
        const int j  = i - NA;
        const int jj = j & 7;
        const int q  = (j >> 3) & 3;
        const int d  = (j >> 5) & 15;
        const int kp = (j >> 9) % 5;
        const int g  = j / 2560;
        const int c  = (q & 1) * 8 + jj;
        const int k  = 2 * kp + (q >> 1);
        const float v = (k < KKn) ? w_def[((g * CGn + d) * CGn + c) * KKn + k] : 0.f;
        ((__hip_bfloat16*)(ws + WMF_BASE))[j] = __float2bfloat16(v);
    } else {
        // halo zeroing: 388 border pixels per batch, 128 B each
        const int hidx = i - (NA + NW);
        if (hidx < Bn * 388) {
            const int b = hidx / 388;
            const int h = hidx % 388;
            int py, px;
            if (h < 98)       { py = 0;           px = h;        }
            else if (h < 196) { py = 97;          px = h - 98;   }
            else if (h < 292) { py = h - 196 + 1; px = 0;        }
            else              { py = h - 292 + 1; px = 97;       }
            f32x4 z = {0.f, 0.f, 0.f, 0.f};
            f32x4* p = (f32x4*)((ushort_t*)(ws + XH_BASE)
                       + ((size_t)b * XH_PIX + py * PW + px) * Cn);
            #pragma unroll
            for (int j2 = 0; j2 < 8; j2++) p[j2] = z;
        }
    }
}

// ---------------------------------------------------------------------------
// Kernel 1: offset conv as MFMA GEMM: out[o][pos] (o<18, K = 64ci x 9tap).
// Wave = 16 pos. Lane (pr=l&15, q=l>>4). 18 kappa-steps; per step: one B-load
// + two A-frag loads; 2 MFMAs. asm pipeline depth 6, counted vmcnt.
// ---------------------------------------------------------------------------
__global__ __launch_bounds__(256) void offset_conv_v4(
    const float* __restrict__ ws, const float* __restrict__ bias,
    float* __restrict__ offs)
{
    // grid = 576 = 8 * 72 : XCD-swizzled
    const int bid = (blockIdx.x & 7) * 72 + (blockIdx.x >> 3);
    const int b = bid / 144;
    const int r = bid % 144;
    const int wave = threadIdx.x >> 6;
    const int lane = threadIdx.x & 63;
    const int pr = lane & 15, q = lane >> 4;
    const int pos0 = r * 64 + wave * 16;
    const int pos = pos0 + pr;
    const int ho = pos / Wn, wo = pos % Wn;
    const unsigned basep = (unsigned)(ho * PW + wo) * 128u;

    const ushort_t* xhb = (const ushort_t*)(ws + XH_BASE) + (size_t)b * XH_PIX * Cn;
    const ushort_t* awf = (const ushort_t*)(ws + AWF_BASE);
    const unsigned pa = (unsigned)(pr * 64 + q * 16);

    f32x4 bi4 = *(const f32x4*)(bias + q * 4);
    f32x2 bi2 = *(const f32x2*)(bias + 16);
    asm volatile("" : "+v"(bi4));
    asm volatile("" : "+v"(bi2));
    asm volatile("s_waitcnt vmcnt(0)" ::: "memory");
    __builtin_amdgcn_sched_barrier(0);

    short8v bfr[6], a0f[6], a1f[6];
    int kk = q, co = 0;          // invariant: u = s*4+q = 9*co + kk
    f32x4 acc0 = {0.f,0.f,0.f,0.f}, acc1 = {0.f,0.f,0.f,0.f};

#define OISSUE(S) { \
    const int ki = kk / 3, kj = kk % 3; \
    const unsigned voff = basep + (unsigned)(ki * PW + kj) * 128u + (unsigned)co * 16u; \
    asm volatile("global_load_dwordx4 %0, %1, %2" : "=v"(bfr[(S)%6]) : "v"(voff), "s"(xhb)); \
    const unsigned aoff = pa + (unsigned)(S) * 2048u; \
    asm volatile("global_load_dwordx4 %0, %1, %2" : "=v"(a0f[(S)%6]) : "v"(aoff), "s"(awf)); \
    asm volatile("global_load_dwordx4 %0, %1, %2" : "=v"(a1f[(S)%6]) : "v"(aoff + 1024u), "s"(awf)); \
    kk += 4; const int cy_ = (kk >= 9) ? 1 : 0; co += cy_; kk -= cy_ * 9; }

#define OCONS(S, N) { \
    asm volatile("s_waitcnt vmcnt(" #N ")" ::: "memory"); \
    __builtin_amdgcn_sched_barrier(0); \
    acc0 = __builtin_amdgcn_mfma_f32_16x16x32_bf16(a0f[(S)%6], bfr[(S)%6], acc0, 0, 0, 0); \
    acc1 = __builtin_amdgcn_mfma_f32_16x16x32_bf16(a1f[(S)%6], bfr[(S)%6], acc1, 0, 0, 0); }

    OISSUE(0) OISSUE(1) OISSUE(2) OISSUE(3) OISSUE(4) OISSUE(5)
    OCONS(0, 15) OISSUE(6)
    OCONS(1, 15) OISSUE(7)
    OCONS(2, 15) OISSUE(8)
    OCONS(3, 15) OISSUE(9)
    OCONS(4, 15) OISSUE(10)
    OCONS(5, 15) OISSUE(11)
    OCONS(6, 15) OISSUE(12)
    OCONS(7, 15) OISSUE(13)
    OCONS(8, 15) OISSUE(14)
    OCONS(9, 15) OISSUE(15)
    OCONS(10, 15) OISSUE(16)
    OCONS(11, 15) OISSUE(17)
    OCONS(12, 15)
    OCONS(13, 12)
    OCONS(14, 9)
    OCONS(15, 6)
    OCONS(16, 3)
    OCONS(17, 0)
#undef OISSUE
#undef OCONS

    float* dst = offs + (size_t)(b * HWn + pos0 + pr) * NOFF + q * 4;
    f32x2 s01; s01.x = acc0[0] + bi4.x; s01.y = acc0[1] + bi4.y;
    f32x2 s23; s23.x = acc0[2] + bi4.z; s23.y = acc0[3] + bi4.w;
    *(f32x2*)dst = s01;
    *(f32x2*)(dst + 2) = s23;
    if (q == 0) {
        f32x2 s67; s67.x = acc1[0] + bi2.x; s67.y = acc1[1] + bi2.y;
        *(f32x2*)(offs + (size_t)(b * HWn + pos0 + pr) * NOFF + 16) = s67;
    }
}

// ---------------------------------------------------------------------------
// Kernel 2: deformable conv via MFMA, kappa = ch + 16*tap, on padded xh.
// EXACT R11-passing v10 structure: 3-pair pipeline, counted vmcnt(8/8/8/4/0),
// pairs 3 and 4 issued after the kp=0 / kp=1 MFMAs.
// ---------------------------------------------------------------------------
#define GLOAD4(dst, off_) \
    asm volatile("global_load_dwordx4 %0, %1, %2" \
                 : "=v"(dst) : "v"(off_), "s"(xhb))

__global__ __launch_bounds__(256) void deform_v10(
    const float* __restrict__ ws, float* __restrict__ out)
{
    const float* __restrict__ off2 = ws + OFF_BASE;
    const short8v* __restrict__ wmf = (const short8v*)(ws + WMF_BASE);

    // grid = 2304 = 8 * 288: XCD-swizzled
    const int bid = (blockIdx.x & 7) * 288 + (blockIdx.x >> 3);
    const int nbb = HWn / 64;              // 144 blocks per (b,g)
    const int bg  = bid / nbb;
    const int g   = bg & (Gn - 1);
    const int b   = bg >> 2;
    const int wave = threadIdx.x >> 6;
    const int lane = threadIdx.x & 63;
    const int pr   = lane & 15;
    const int q    = lane >> 4;
    const int half = q & 1;
    const int tp   = q >> 1;
    const int pos0 = (bid % nbb) * 64 + wave * 16;
    const int pos  = pos0 + pr;
    const int ho = pos / Wn, wo = pos % Wn;

    const f32x2* op2 = (const f32x2*)(off2 + (size_t)(b * HWn + pos) * NOFF);
    f32x2 o2[5];
    #pragma unroll
    for (int kp = 0; kp < 5; kp++) {
        int kq = 2 * kp + tp; if (kq > 8) kq = 8;   // tap9 -> dummy (cwt zeroed)
        o2[kp] = op2[kq];
    }
    short8v a[5];
    #pragma unroll
    for (int kp = 0; kp < 5; kp++)
        a[kp] = wmf[((g * 5 + kp) * CGn + pr) * 4 + q];

    const ushort_t* xhb = (const ushort_t*)(ws + XH_BASE) + (size_t)b * XH_PIX * Cn;
    const unsigned choff = (unsigned)(g * 32 + half * 16);

    #pragma unroll
    for (int kp = 0; kp < 5; kp++) {
        asm volatile("" : "+v"(o2[kp]));
        asm volatile("" : "+v"(a[kp]));
    }
    asm volatile("s_waitcnt vmcnt(0)" ::: "memory");
    __builtin_amdgcn_sched_barrier(0);

    float cwt[5][4];
    f32x4 dat[5][4];

#define PAIRSETUP(KP)                                                      \
  {                                                                        \
    const int k  = 2 * (KP) + tp;                                          \
    const int ki = k / 3, kj = k - 3 * ki;                                 \
    const float m = (k <= 8) ? 1.f : 0.f;                                  \
    const float ysf = (float)(ho - 1 + ki) + o2[KP].x;                     \
    const float xsf = (float)(wo - 1 + kj) + o2[KP].y;                     \
    const float y0f = floorf(ysf), x0f = floorf(xsf);                      \
    const int   y0  = (int)y0f,    x0  = (int)x0f;                         \
    const float wy1 = ysf - y0f, wx1 = xsf - x0f;                          \
    const float wy0 = 1.f - wy1, wx0 = 1.f - wx1;                          \
    const bool vy0 = (y0 >= 0)  && (y0 < Hn);                              \
    const bool vy1 = (y0 >= -1) && (y0 < Hn - 1);                          \
    const bool vx0 = (x0 >= 0)  && (x0 < Wn);                              \
    const bool vx1 = (x0 >= -1) && (x0 < Wn - 1);                          \
    const int cy0 = min(max(y0,     0), Hn - 1);                           \
    const int cy1 = min(max(y0 + 1, 0), Hn - 1);                           \
    const int cx0 = min(max(x0,     0), Wn - 1);                           \
    const int cx1 = min(max(x0 + 1, 0), Wn - 1);                           \
    cwt[KP][0] = m * wy0 * wx0 * ((vy0 && vx0) ? 1.f : 0.f);               \
    cwt[KP][1] = m * wy0 * wx1 * ((vy0 && vx1) ? 1.f : 0.f);               \
    cwt[KP][2] = m * wy1 * wx0 * ((vy1 && vx0) ? 1.f : 0.f);               \
    cwt[KP][3] = m * wy1 * wx1 * ((vy1 && vx1) ? 1.f : 0.f);               \
    const unsigned v00 = (unsigned)((cy0 + 1) * PW + cx0 + 1) * 128u + choff; \
    const unsigned v01 = (unsigned)((cy0 + 1) * PW + cx1 + 1) * 128u + choff; \
    const unsigned v10 = (unsigned)((cy1 + 1) * PW + cx0 + 1) * 128u + choff; \
    const unsigned v11 = (unsigned)((cy1 + 1) * PW + cx1 + 1) * 128u + choff; \
    GLOAD4(dat[KP][0], v00);                                               \
    GLOAD4(dat[KP][1], v01);                                               \
    GLOAD4(dat[KP][2], v10);                                               \
    GLOAD4(dat[KP][3], v11);                                               \
  }

    PAIRSETUP(0); PAIRSETUP(1); PAIRSETUP(2);

    f32x4 acc = {0.f, 0.f, 0.f, 0.f};

    #pragma unroll
    for (int kp = 0; kp < 5; kp++) {
        if (kp <= 2)      asm volatile("s_waitcnt vmcnt(8)" ::: "memory");
        else if (kp == 3) asm volatile("s_waitcnt vmcnt(4)" ::: "memory");
        else              asm volatile("s_waitcnt vmcnt(0)" ::: "memory");
        __builtin_amdgcn_sched_barrier(0);

        float s[8] = {0.f,0.f,0.f,0.f,0.f,0.f,0.f,0.f};
        #pragma unroll
        for (int c4 = 0; c4 < 4; c4++) {
            const float w = cwt[kp][c4];
            const uint4v u = *reinterpret_cast<const uint4v*>(&dat[kp][c4]);
            #pragma unroll
            for (int w2 = 0; w2 < 4; w2++) {
                unsigned lo = u[w2] << 16;
                unsigned hi = u[w2] & 0xffff0000u;
                s[2*w2]   += w * *reinterpret_cast<float*>(&lo);
                s[2*w2+1] += w * *reinterpret_cast<float*>(&hi);
            }
        }
        short8v fr;
        #pragma unroll
        for (int j = 0; j < 8; j++) fr[j] = f2bs(s[j]);
        acc = __builtin_amdgcn_mfma_f32_16x16x32_bf16(a[kp], fr, acc, 0, 0, 0);

        if (kp == 0) PAIRSETUP(3);
        if (kp == 1) PAIRSETUP(4);
    }

    float* op = out + (size_t)(b * Cn + g * CGn) * HWn + pos0;
    #pragma unroll
    for (int r = 0; r < 4; r++)
        op[(q * 4 + r) * HWn + pr] = acc[r];
}

// ---------------------------------------------------------------------------
extern "C" void kernel_launch(void* const* d_in, const int* in_sizes, int n_in,
                              void* d_out, int out_size, void* d_ws, size_t ws_size,
                              hipStream_t stream) {
    const float* x     = (const float*)d_in[0];
    const float* w_off = (const float*)d_in[1];
    const float* b_off = (const float*)d_in[2];
    const float* w_def = (const float*)d_in[3];
    float* out = (float*)d_out;
    float* ws  = (float*)d_ws;

    const int n_pack = 18432 + 10240;                 // 112 blocks
    const int nblk = NTRB + n_pack / 256 + 7;         // 576 + 112 + 7 halo
    prep_all<<<nblk, 256, 0, stream>>>(x, w_off, w_def, ws);

    offset_conv_v4<<<576, 256, 0, stream>>>(ws, b_off, ws + OFF_BASE);

    deform_v10<<<Bn * Gn * (HWn / 64), 256, 0, stream>>>(ws, out);
}

// Round 15
// 43.978 us; speedup vs baseline: 1.2335x; 1.1459x over previous
//
#include <hip/hip_runtime.h>
#include <hip/hip_bf16.h>

// Problem constants
#define Bn   4
#define Cn   64
#define Hn   96
#define Wn   96
#define Gn   4
#define CGn  16      // Cn / Gn
#define KKn  9
#define NOFF 18      // 2*K*K offset channels
#define HWn  (Hn*Wn) // 9216
#define PW   98      // padded width/height (1-px halo)
#define XH_PIX (PW*PW)   // 9604 pixels per batch

// ws layout (floats)
#define OFF_BASE  0                        // B*HW*18 pos-major offsets (663552 fl)
#define AWF_BASE  (Bn*HWn*NOFF)            // offconv A-frags: 18432 bf16 = 9216 fl
#define WMF_BASE  (AWF_BASE + 9216)        // deform A-frags: 10240 bf16 = 5120 fl
#define XH_BASE   (WMF_BASE + 5120)        // xh[b][98][98][64] bf16 = 2458624 sh
#define XG_BASE   (XH_BASE + 1229312)      // xg[b][g][pos][16] bf16 = 2359296 sh

typedef __attribute__((ext_vector_type(8))) short short8v;   // 8 bf16 = 4 VGPR
typedef __attribute__((ext_vector_type(4))) float f32x4;
typedef __attribute__((ext_vector_type(2))) float f32x2;
typedef __attribute__((ext_vector_type(4))) unsigned int uint4v;
typedef unsigned short ushort_t;

__device__ inline short f2bs(float v) {
    __hip_bfloat16 h = __float2bfloat16(v);
    return *reinterpret_cast<short*>(&h);
}
__device__ inline unsigned pack2bf(float lo, float hi) {
    return (unsigned)(ushort_t)f2bs(lo) | ((unsigned)(ushort_t)f2bs(hi) << 16);
}

// ---------------------------------------------------------------------------
// Kernel 0 (fused). Blocks [0,576): transpose x NCHW fp32 -> BOTH
//   xh[b][py][px][64] (halo image, offconv) and
//   xg[b][g][pos][16]  (compact group-major, deform: 32B pixel lines).
// Blocks [576,688): pack offconv + deform A-frags.
// Blocks [688,695): zero the 1-px xh halo.
// ---------------------------------------------------------------------------
#define NTRB (Bn * (HWn / 64))   // 576 transpose blocks
__global__ __launch_bounds__(256) void prep_all(
    const float* __restrict__ x, const float* __restrict__ w_off,
    const float* __restrict__ w_def, float* __restrict__ ws)
{
    __shared__ float t[64][65];
    if (blockIdx.x < NTRB) {
        const int nb = HWn / 64;               // 144
        const int b  = blockIdx.x / nb;
        const int p0 = (blockIdx.x % nb) * 64;
        ushort_t* xh = (ushort_t*)(ws + XH_BASE);
        ushort_t* xg = (ushort_t*)(ws + XG_BASE);
        for (int i = threadIdx.x; i < 64 * 64; i += 256) {
            const int c = i >> 6, l = i & 63;
            t[c][l] = x[(b * Cn + c) * HWn + p0 + l];
        }
        __syncthreads();
        for (int i = threadIdx.x; i < 64 * 32; i += 256) {
            const int l = i >> 5, cp = i & 31;      // cp = channel pair
            const int pos = p0 + l;
            const int ho = pos / Wn, wo = pos % Wn;
            const unsigned pk = pack2bf(t[cp * 2][l], t[cp * 2 + 1][l]);
            *(unsigned*)(xh + ((size_t)b * XH_PIX + (ho + 1) * PW + wo + 1) * Cn
                             + cp * 2) = pk;
            const int g = cp >> 3, pg = cp & 7;     // group, pair-in-group
            *(unsigned*)(xg + ((size_t)(b * Gn + g) * HWn + pos) * CGn
                             + pg * 2) = pk;
        }
        return;
    }
    const int i = (blockIdx.x - NTRB) * 256 + threadIdx.x;
    const int NA = 18 * 2 * 16 * 4 * 8;    // 18432 offconv A-frag elems
    const int NW = Gn * 5 * CGn * 4 * 8;   // 10240 deform A-frag elems
    if (i < NA) {
        const int jj  = i & 7;
        const int q   = (i >> 3) & 3;
        const int row = (i >> 5) & 15;
        const int tt  = (i >> 9) & 1;
        const int s   = i >> 10;           // 0..17
        const int u   = s * 4 + q;
        const int k   = u % 9, co = u / 9;
        const int ci  = co * 8 + jj;
        const int o   = tt * 16 + row;
        const float v = (o < NOFF) ? w_off[(o * Cn + ci) * KKn + k] : 0.f;
        ((__hip_bfloat16*)(ws + AWF_BASE))[i] = __float2bfloat16(v);
    } else if (i < NA + NW) {
        const int j  = i - NA;
        const int jj = j & 7;
        const int q  = (j >> 3) & 3;
        const int d  = (j >> 5) & 15;
        const int kp = (j >> 9) % 5;
        const int g  = j / 2560;
        const int c  = (q & 1) * 8 + jj;
        const int k  = 2 * kp + (q >> 1);
        const float v = (k < KKn) ? w_def[((g * CGn + d) * CGn + c) * KKn + k] : 0.f;
        ((__hip_bfloat16*)(ws + WMF_BASE))[j] = __float2bfloat16(v);
    } else {
        // xh halo zeroing: 388 border pixels per batch, 128 B each
        const int hidx = i - (NA + NW);
        if (hidx < Bn * 388) {
            const int b = hidx / 388;
            const int h = hidx % 388;
            int py, px;
            if (h < 98)       { py = 0;           px = h;        }
            else if (h < 196) { py = 97;          px = h - 98;   }
            else if (h < 292) { py = h - 196 + 1; px = 0;        }
            else              { py = h - 292 + 1; px = 97;       }
            f32x4 z = {0.f, 0.f, 0.f, 0.f};
            f32x4* p = (f32x4*)((ushort_t*)(ws + XH_BASE)
                       + ((size_t)b * XH_PIX + py * PW + px) * Cn);
            #pragma unroll
            for (int j2 = 0; j2 < 8; j2++) p[j2] = z;
        }
    }
}

// ---------------------------------------------------------------------------
// Kernel 1: offset conv as MFMA GEMM on the halo image (no bounds checks).
// Wave = 16 pos. 18 kappa-steps; per step: one B-load + two A-frag loads;
// 2 MFMAs. asm pipeline depth 6, counted vmcnt. (proven R13)
// ---------------------------------------------------------------------------
__global__ __launch_bounds__(256) void offset_conv_v4(
    const float* __restrict__ ws, const float* __restrict__ bias,
    float* __restrict__ offs)
{
    // grid = 576 = 8 * 72 : XCD-swizzled
    const int bid = (blockIdx.x & 7) * 72 + (blockIdx.x >> 3);
    const int b = bid / 144;
    const int r = bid % 144;
    const int wave = threadIdx.x >> 6;
    const int lane = threadIdx.x & 63;
    const int pr = lane & 15, q = lane >> 4;
    const int pos0 = r * 64 + wave * 16;
    const int pos = pos0 + pr;
    const int ho = pos / Wn, wo = pos % Wn;
    const unsigned basep = (unsigned)(ho * PW + wo) * 128u;

    const ushort_t* xhb = (const ushort_t*)(ws + XH_BASE) + (size_t)b * XH_PIX * Cn;
    const ushort_t* awf = (const ushort_t*)(ws + AWF_BASE);
    const unsigned pa = (unsigned)(pr * 64 + q * 16);

    f32x4 bi4 = *(const f32x4*)(bias + q * 4);
    f32x2 bi2 = *(const f32x2*)(bias + 16);
    asm volatile("" : "+v"(bi4));
    asm volatile("" : "+v"(bi2));
    asm volatile("s_waitcnt vmcnt(0)" ::: "memory");
    __builtin_amdgcn_sched_barrier(0);

    short8v bfr[6], a0f[6], a1f[6];
    int kk = q, co = 0;          // invariant: u = s*4+q = 9*co + kk
    f32x4 acc0 = {0.f,0.f,0.f,0.f}, acc1 = {0.f,0.f,0.f,0.f};

#define OISSUE(S) { \
    const int ki = kk / 3, kj = kk % 3; \
    const unsigned voff = basep + (unsigned)(ki * PW + kj) * 128u + (unsigned)co * 16u; \
    asm volatile("global_load_dwordx4 %0, %1, %2" : "=v"(bfr[(S)%6]) : "v"(voff), "s"(xhb)); \
    const unsigned aoff = pa + (unsigned)(S) * 2048u; \
    asm volatile("global_load_dwordx4 %0, %1, %2" : "=v"(a0f[(S)%6]) : "v"(aoff), "s"(awf)); \
    asm volatile("global_load_dwordx4 %0, %1, %2" : "=v"(a1f[(S)%6]) : "v"(aoff + 1024u), "s"(awf)); \
    kk += 4; const int cy_ = (kk >= 9) ? 1 : 0; co += cy_; kk -= cy_ * 9; }

#define OCONS(S, N) { \
    asm volatile("s_waitcnt vmcnt(" #N ")" ::: "memory"); \
    __builtin_amdgcn_sched_barrier(0); \
    acc0 = __builtin_amdgcn_mfma_f32_16x16x32_bf16(a0f[(S)%6], bfr[(S)%6], acc0, 0, 0, 0); \
    acc1 = __builtin_amdgcn_mfma_f32_16x16x32_bf16(a1f[(S)%6], bfr[(S)%6], acc1, 0, 0, 0); }

    OISSUE(0) OISSUE(1) OISSUE(2) OISSUE(3) OISSUE(4) OISSUE(5)
    OCONS(0, 15) OISSUE(6)
    OCONS(1, 15) OISSUE(7)
    OCONS(2, 15) OISSUE(8)
    OCONS(3, 15) OISSUE(9)
    OCONS(4, 15) OISSUE(10)
    OCONS(5, 15) OISSUE(11)
    OCONS(6, 15) OISSUE(12)
    OCONS(7, 15) OISSUE(13)
    OCONS(8, 15) OISSUE(14)
    OCONS(9, 15) OISSUE(15)
    OCONS(10, 15) OISSUE(16)
    OCONS(11, 15) OISSUE(17)
    OCONS(12, 15)
    OCONS(13, 12)
    OCONS(14, 9)
    OCONS(15, 6)
    OCONS(16, 3)
    OCONS(17, 0)
#undef OISSUE
#undef OCONS

    float* dst = offs + (size_t)(b * HWn + pos0 + pr) * NOFF + q * 4;
    f32x2 s01; s01.x = acc0[0] + bi4.x; s01.y = acc0[1] + bi4.y;
    f32x2 s23; s23.x = acc0[2] + bi4.z; s23.y = acc0[3] + bi4.w;
    *(f32x2*)dst = s01;
    *(f32x2*)(dst + 2) = s23;
    if (q == 0) {
        f32x2 s67; s67.x = acc1[0] + bi2.x; s67.y = acc1[1] + bi2.y;
        *(f32x2*)(offs + (size_t)(b * HWn + pos0 + pr) * NOFF + 16) = s67;
    }
}

// ---------------------------------------------------------------------------
// Kernel 2: deformable conv via MFMA, EXACT R8-proven v9 structure:
// compact xg layout (32B pixel lines, whole line consumed by the wave),
// clamp+mask sampling, 3-pair pipeline, counted vmcnt(8/8/8/4/0).
// ---------------------------------------------------------------------------
#define GLOAD4(dst, off_) \
    asm volatile("global_load_dwordx4 %0, %1, %2" \
                 : "=v"(dst) : "v"(off_), "s"(xgb))

__global__ __launch_bounds__(256) void deform_v9(
    const float* __restrict__ ws, float* __restrict__ out)
{
    const float* __restrict__ off2 = ws + OFF_BASE;
    const short8v* __restrict__ wmf = (const short8v*)(ws + WMF_BASE);

    // grid = 2304 = 8 * 288: XCD-swizzled
    const int bid = (blockIdx.x & 7) * 288 + (blockIdx.x >> 3);
    const int nbb = HWn / 64;              // 144 blocks per (b,g)
    const int bg  = bid / nbb;
    const int g   = bg & (Gn - 1);
    const int b   = bg >> 2;
    const int wave = threadIdx.x >> 6;
    const int lane = threadIdx.x & 63;
    const int pr   = lane & 15;
    const int q    = lane >> 4;
    const int half = q & 1;
    const int tp   = q >> 1;
    const int pos0 = (bid % nbb) * 64 + wave * 16;
    const int pos  = pos0 + pr;
    const int ho = pos / Wn, wo = pos % Wn;

    const f32x2* op2 = (const f32x2*)(off2 + (size_t)(b * HWn + pos) * NOFF);
    f32x2 o2[5];
    #pragma unroll
    for (int kp = 0; kp < 5; kp++) {
        int kq = 2 * kp + tp; if (kq > 8) kq = 8;   // tap9 -> dummy (cwt zeroed)
        o2[kp] = op2[kq];
    }
    short8v a[5];
    #pragma unroll
    for (int kp = 0; kp < 5; kp++)
        a[kp] = wmf[((g * 5 + kp) * CGn + pr) * 4 + q];

    const ushort_t* xgb = (const ushort_t*)(ws + XG_BASE)
                        + (size_t)(b * Gn + g) * HWn * CGn;
    const unsigned hoff = (unsigned)half * 16u;

    #pragma unroll
    for (int kp = 0; kp < 5; kp++) {
        asm volatile("" : "+v"(o2[kp]));
        asm volatile("" : "+v"(a[kp]));
    }
    asm volatile("s_waitcnt vmcnt(0)" ::: "memory");
    __builtin_amdgcn_sched_barrier(0);

    float cwt[5][4];
    f32x4 dat[5][4];

#define PAIRSETUP(KP)                                                      \
  {                                                                        \
    const int k  = 2 * (KP) + tp;                                          \
    const int ki = k / 3, kj = k - 3 * ki;                                 \
    const float m = (k <= 8) ? 1.f : 0.f;                                  \
    const float ysf = (float)(ho - 1 + ki) + o2[KP].x;                     \
    const float xsf = (float)(wo - 1 + kj) + o2[KP].y;                     \
    const float y0f = floorf(ysf), x0f = floorf(xsf);                      \
    const int   y0  = (int)y0f,    x0  = (int)x0f;                         \
    const float wy1 = ysf - y0f, wx1 = xsf - x0f;                          \
    const float wy0 = 1.f - wy1, wx0 = 1.f - wx1;                          \
    const bool vy0 = (y0 >= 0)  && (y0 < Hn);                              \
    const bool vy1 = (y0 >= -1) && (y0 < Hn - 1);                          \
    const bool vx0 = (x0 >= 0)  && (x0 < Wn);                              \
    const bool vx1 = (x0 >= -1) && (x0 < Wn - 1);                          \
    const int cy0 = min(max(y0,     0), Hn - 1);                           \
    const int cy1 = min(max(y0 + 1, 0), Hn - 1);                           \
    const int cx0 = min(max(x0,     0), Wn - 1);                           \
    const int cx1 = min(max(x0 + 1, 0), Wn - 1);                           \
    cwt[KP][0] = m * wy0 * wx0 * ((vy0 && vx0) ? 1.f : 0.f);               \
    cwt[KP][1] = m * wy0 * wx1 * ((vy0 && vx1) ? 1.f : 0.f);               \
    cwt[KP][2] = m * wy1 * wx0 * ((vy1 && vx0) ? 1.f : 0.f);               \
    cwt[KP][3] = m * wy1 * wx1 * ((vy1 && vx1) ? 1.f : 0.f);               \
    const unsigned v00 = (unsigned)(cy0 * Wn + cx0) * 32u + hoff;          \
    const unsigned v01 = (unsigned)(cy0 * Wn + cx1) * 32u + hoff;          \
    const unsigned v10 = (unsigned)(cy1 * Wn + cx0) * 32u + hoff;          \
    const unsigned v11 = (unsigned)(cy1 * Wn + cx1) * 32u + hoff;          \
    GLOAD4(dat[KP][0], v00);                                               \
    GLOAD4(dat[KP][1], v01);                                               \
    GLOAD4(dat[KP][2], v10);                                               \
    GLOAD4(dat[KP][3], v11);                                               \
  }

    PAIRSETUP(0); PAIRSETUP(1); PAIRSETUP(2);

    f32x4 acc = {0.f, 0.f, 0.f, 0.f};

    #pragma unroll
    for (int kp = 0; kp < 5; kp++) {
        if (kp <= 2)      asm volatile("s_waitcnt vmcnt(8)" ::: "memory");
        else if (kp == 3) asm volatile("s_waitcnt vmcnt(4)" ::: "memory");
        else              asm volatile("s_waitcnt vmcnt(0)" ::: "memory");
        __builtin_amdgcn_sched_barrier(0);

        float s[8] = {0.f,0.f,0.f,0.f,0.f,0.f,0.f,0.f};
        #pragma unroll
        for (int c4 = 0; c4 < 4; c4++) {
            const float w = cwt[kp][c4];
            const uint4v u = *reinterpret_cast<const uint4v*>(&dat[kp][c4]);
            #pragma unroll
            for (int w2 = 0; w2 < 4; w2++) {
                unsigned lo = u[w2] << 16;
                unsigned hi = u[w2] & 0xffff0000u;
                s[2*w2]   += w * *reinterpret_cast<float*>(&lo);
                s[2*w2+1] += w * *reinterpret_cast<float*>(&hi);
            }
        }
        short8v fr;
        #pragma unroll
        for (int j = 0; j < 8; j++) fr[j] = f2bs(s[j]);
        acc = __builtin_amdgcn_mfma_f32_16x16x32_bf16(a[kp], fr, acc, 0, 0, 0);

        if (kp == 0) PAIRSETUP(3);
        if (kp == 1) PAIRSETUP(4);
    }

    float* op = out + (size_t)(b * Cn + g * CGn) * HWn + pos0;
    #pragma unroll
    for (int r = 0; r < 4; r++)
        op[(q * 4 + r) * HWn + pr] = acc[r];
}

// ---------------------------------------------------------------------------
extern "C" void kernel_launch(void* const* d_in, const int* in_sizes, int n_in,
                              void* d_out, int out_size, void* d_ws, size_t ws_size,
                              hipStream_t stream) {
    const float* x     = (const float*)d_in[0];
    const float* w_off = (const float*)d_in[1];
    const float* b_off = (const float*)d_in[2];
    const float* w_def = (const float*)d_in[3];
    float* out = (float*)d_out;
    float* ws  = (float*)d_ws;

    const int n_pack = 18432 + 10240;                 // 112 blocks
    const int nblk = NTRB + n_pack / 256 + 7;         // 576 + 112 + 7 halo
    prep_all<<<nblk, 256, 0, stream>>>(x, w_off, w_def, ws);

    offset_conv_v4<<<576, 256, 0, stream>>>(ws, b_off, ws + OFF_BASE);

    deform_v9<<<Bn * Gn * (HWn / 64), 256, 0, stream>>>(ws, out);
}

// Round 16
// 37.266 us; speedup vs baseline: 1.4557x; 1.1801x over previous
//
#include <hip/hip_runtime.h>
#include <hip/hip_bf16.h>

// Problem constants
#define Bn   4
#define Cn   64
#define Hn   96
#define Wn   96
#define Gn   4
#define CGn  16      // Cn / Gn
#define KKn  9
#define NOFF 18      // 2*K*K offset channels
#define HWn  (Hn*Wn) // 9216
#define PW   98      // padded width/height (1-px halo)
#define XH_PIX (PW*PW)   // 9604 pixels per plane
#define PLANE_B (XH_PIX * CGn * 2)   // 307328 bytes per (b,g) plane

// ws layout (floats)
#define OFF_BASE  0                        // B*HW*18 pos-major offsets (663552 fl)
#define AWF_BASE  (Bn*HWn*NOFF)            // offconv A-frags: 18432 bf16 = 9216 fl
#define WMF_BASE  (AWF_BASE + 9216)        // deform A-frags: 10240 bf16 = 5120 fl
#define XGH_BASE  (WMF_BASE + 5120)        // xgh[b][g][98*98][16] bf16 = 2458624 sh

typedef __attribute__((ext_vector_type(8))) short short8v;   // 8 bf16 = 4 VGPR
typedef __attribute__((ext_vector_type(4))) float f32x4;
typedef __attribute__((ext_vector_type(2))) float f32x2;
typedef __attribute__((ext_vector_type(4))) unsigned int uint4v;
typedef unsigned short ushort_t;

__device__ inline short f2bs(float v) {
    __hip_bfloat16 h = __float2bfloat16(v);
    return *reinterpret_cast<short*>(&h);
}
__device__ inline unsigned pack2bf(float lo, float hi) {
    return (unsigned)(ushort_t)f2bs(lo) | ((unsigned)(ushort_t)f2bs(hi) << 16);
}

// ---------------------------------------------------------------------------
// Kernel 0 (fused). Blocks [0,576): transpose x NCHW fp32 -> single halo'd
// group-major bf16 image xgh[b][g][py*98+px][16] (serves BOTH consumers).
// Blocks [576,688): pack offconv + deform A-frags.
// Remaining blocks: zero the 1-px halo of all 16 (b,g) planes.
// ---------------------------------------------------------------------------
#define NTRB (Bn * (HWn / 64))   // 576 transpose blocks
#define NHALO (Bn * Gn * 388)    // 6208 halo pixels, 32 B each
__global__ __launch_bounds__(256) void prep_all(
    const float* __restrict__ x, const float* __restrict__ w_off,
    const float* __restrict__ w_def, float* __restrict__ ws)
{
    __shared__ float t[64][65];
    if (blockIdx.x < NTRB) {
        const int nb = HWn / 64;               // 144
        const int b  = blockIdx.x / nb;
        const int p0 = (blockIdx.x % nb) * 64;
        ushort_t* xgh = (ushort_t*)(ws + XGH_BASE);
        for (int i = threadIdx.x; i < 64 * 64; i += 256) {
            const int c = i >> 6, l = i & 63;
            t[c][l] = x[(b * Cn + c) * HWn + p0 + l];
        }
        __syncthreads();
        for (int i = threadIdx.x; i < 64 * 32; i += 256) {
            const int l = i >> 5, cp = i & 31;      // cp = channel pair
            const int pos = p0 + l;
            const int ho = pos / Wn, wo = pos % Wn;
            const unsigned pk = pack2bf(t[cp * 2][l], t[cp * 2 + 1][l]);
            const int g = cp >> 3, pg = cp & 7;     // group, pair-in-group
            *(unsigned*)(xgh + ((size_t)(b * Gn + g) * XH_PIX
                                + (ho + 1) * PW + (wo + 1)) * CGn + pg * 2) = pk;
        }
        return;
    }
    const int i = (blockIdx.x - NTRB) * 256 + threadIdx.x;
    const int NA = 18 * 2 * 16 * 4 * 8;    // 18432 offconv A-frag elems
    const int NW = Gn * 5 * CGn * 4 * 8;   // 10240 deform A-frag elems
    if (i < NA) {
        const int jj  = i & 7;
        const int q   = (i >> 3) & 3;
        const int row = (i >> 5) & 15;
        const int tt  = (i >> 9) & 1;
        const int s   = i >> 10;           // 0..17
        const int u   = s * 4 + q;
        const int k   = u % 9, co = u / 9;
        const int ci  = co * 8 + jj;
        const int o   = tt * 16 + row;
        const float v = (o < NOFF) ? w_off[(o * Cn + ci) * KKn + k] : 0.f;
        ((__hip_bfloat16*)(ws + AWF_BASE))[i] = __float2bfloat16(v);
    } else if (i < NA + NW) {
        const int j  = i - NA;
        const int jj = j & 7;
        const int q  = (j >> 3) & 3;
        const int d  = (j >> 5) & 15;
        const int kp = (j >> 9) % 5;
        const int g  = j / 2560;
        const int c  = (q & 1) * 8 + jj;
        const int k  = 2 * kp + (q >> 1);
        const float v = (k < KKn) ? w_def[((g * CGn + d) * CGn + c) * KKn + k] : 0.f;
        ((__hip_bfloat16*)(ws + WMF_BASE))[j] = __float2bfloat16(v);
    } else {
        // halo zeroing: 388 border pixels per (b,g) plane, 32 B each
        const int hidx = i - (NA + NW);
        if (hidx < NHALO) {
            const int plane = hidx / 388;       // b*4+g
            const int h = hidx % 388;
            int py, px;
            if (h < 98)       { py = 0;           px = h;        }
            else if (h < 196) { py = 97;          px = h - 98;   }
            else if (h < 292) { py = h - 196 + 1; px = 0;        }
            else              { py = h - 292 + 1; px = 97;       }
            f32x4 z = {0.f, 0.f, 0.f, 0.f};
            f32x4* p = (f32x4*)((ushort_t*)(ws + XGH_BASE)
                       + ((size_t)plane * XH_PIX + py * PW + px) * CGn);
            p[0] = z; p[1] = z;
        }
    }
}

// ---------------------------------------------------------------------------
// Kernel 1: offset conv as MFMA GEMM on the halo'd group planes (no bounds
// checks). Wave = 16 pos. 18 kappa-steps; per step: one 16B B-load (8 bf16 ch
// = octet co&1 of group co>>1) + two A-frag loads; 2 MFMAs. Depth-6 pipeline.
// ---------------------------------------------------------------------------
__global__ __launch_bounds__(256) void offset_conv_v4(
    const float* __restrict__ ws, const float* __restrict__ bias,
    float* __restrict__ offs)
{
    // grid = 576 = 8 * 72 : XCD-swizzled
    const int bid = (blockIdx.x & 7) * 72 + (blockIdx.x >> 3);
    const int b = bid / 144;
    const int r = bid % 144;
    const int wave = threadIdx.x >> 6;
    const int lane = threadIdx.x & 63;
    const int pr = lane & 15, q = lane >> 4;
    const int pos0 = r * 64 + wave * 16;
    const int pos = pos0 + pr;
    const int ho = pos / Wn, wo = pos % Wn;
    const unsigned basep = (unsigned)(ho * PW + wo) * 32u;  // halo folds the +1s

    const ushort_t* xhb = (const ushort_t*)(ws + XGH_BASE)
                        + (size_t)b * Gn * XH_PIX * CGn;
    const ushort_t* awf = (const ushort_t*)(ws + AWF_BASE);
    const unsigned pa = (unsigned)(pr * 64 + q * 16);

    f32x4 bi4 = *(const f32x4*)(bias + q * 4);
    f32x2 bi2 = *(const f32x2*)(bias + 16);
    asm volatile("" : "+v"(bi4));
    asm volatile("" : "+v"(bi2));
    asm volatile("s_waitcnt vmcnt(0)" ::: "memory");
    __builtin_amdgcn_sched_barrier(0);

    short8v bfr[6], a0f[6], a1f[6];
    int kk = q, co = 0;          // invariant: u = s*4+q = 9*co + kk
    f32x4 acc0 = {0.f,0.f,0.f,0.f}, acc1 = {0.f,0.f,0.f,0.f};

#define OISSUE(S) { \
    const int ki = kk / 3, kj = kk % 3; \
    const unsigned voff = (unsigned)(co >> 1) * (unsigned)PLANE_B + basep \
                        + (unsigned)(ki * PW + kj) * 32u + (unsigned)(co & 1) * 16u; \
    asm volatile("global_load_dwordx4 %0, %1, %2" : "=v"(bfr[(S)%6]) : "v"(voff), "s"(xhb)); \
    const unsigned aoff = pa + (unsigned)(S) * 2048u; \
    asm volatile("global_load_dwordx4 %0, %1, %2" : "=v"(a0f[(S)%6]) : "v"(aoff), "s"(awf)); \
    asm volatile("global_load_dwordx4 %0, %1, %2" : "=v"(a1f[(S)%6]) : "v"(aoff + 1024u), "s"(awf)); \
    kk += 4; const int cy_ = (kk >= 9) ? 1 : 0; co += cy_; kk -= cy_ * 9; }

#define OCONS(S, N) { \
    asm volatile("s_waitcnt vmcnt(" #N ")" ::: "memory"); \
    __builtin_amdgcn_sched_barrier(0); \
    acc0 = __builtin_amdgcn_mfma_f32_16x16x32_bf16(a0f[(S)%6], bfr[(S)%6], acc0, 0, 0, 0); \
    acc1 = __builtin_amdgcn_mfma_f32_16x16x32_bf16(a1f[(S)%6], bfr[(S)%6], acc1, 0, 0, 0); }

    OISSUE(0) OISSUE(1) OISSUE(2) OISSUE(3) OISSUE(4) OISSUE(5)
    OCONS(0, 15) OISSUE(6)
    OCONS(1, 15) OISSUE(7)
    OCONS(2, 15) OISSUE(8)
    OCONS(3, 15) OISSUE(9)
    OCONS(4, 15) OISSUE(10)
    OCONS(5, 15) OISSUE(11)
    OCONS(6, 15) OISSUE(12)
    OCONS(7, 15) OISSUE(13)
    OCONS(8, 15) OISSUE(14)
    OCONS(9, 15) OISSUE(15)
    OCONS(10, 15) OISSUE(16)
    OCONS(11, 15) OISSUE(17)
    OCONS(12, 15)
    OCONS(13, 12)
    OCONS(14, 9)
    OCONS(15, 6)
    OCONS(16, 3)
    OCONS(17, 0)
#undef OISSUE
#undef OCONS

    float* dst = offs + (size_t)(b * HWn + pos0 + pr) * NOFF + q * 4;
    f32x2 s01; s01.x = acc0[0] + bi4.x; s01.y = acc0[1] + bi4.y;
    f32x2 s23; s23.x = acc0[2] + bi4.z; s23.y = acc0[3] + bi4.w;
    *(f32x2*)dst = s01;
    *(f32x2*)(dst + 2) = s23;
    if (q == 0) {
        f32x2 s67; s67.x = acc1[0] + bi2.x; s67.y = acc1[1] + bi2.y;
        *(f32x2*)(offs + (size_t)(b * HWn + pos0 + pr) * NOFF + 16) = s67;
    }
}

// ---------------------------------------------------------------------------
// Kernel 2: deformable conv via MFMA on the halo'd group plane (32B pixel
// lines). R8-proven v9 structure; NEW: dat/cwt rotated %3 (only 3 pairs live)
// to cut ~40 VGPR -> more resident waves. Counted vmcnt(8/8/8/4/0).
// ---------------------------------------------------------------------------
#define GLOAD4(dst, off_) \
    asm volatile("global_load_dwordx4 %0, %1, %2" \
                 : "=v"(dst) : "v"(off_), "s"(xgb))

__global__ __launch_bounds__(256) void deform_v12(
    const float* __restrict__ ws, float* __restrict__ out)
{
    const float* __restrict__ off2 = ws + OFF_BASE;
    const short8v* __restrict__ wmf = (const short8v*)(ws + WMF_BASE);

    // grid = 2304 = 8 * 288: XCD-swizzled
    const int bid = (blockIdx.x & 7) * 288 + (blockIdx.x >> 3);
    const int nbb = HWn / 64;              // 144 blocks per (b,g)
    const int bg  = bid / nbb;
    const int g   = bg & (Gn - 1);
    const int b   = bg >> 2;
    const int wave = threadIdx.x >> 6;
    const int lane = threadIdx.x & 63;
    const int pr   = lane & 15;
    const int q    = lane >> 4;
    const int half = q & 1;
    const int tp   = q >> 1;
    const int pos0 = (bid % nbb) * 64 + wave * 16;
    const int pos  = pos0 + pr;
    const int ho = pos / Wn, wo = pos % Wn;

    const f32x2* op2 = (const f32x2*)(off2 + (size_t)(b * HWn + pos) * NOFF);
    f32x2 o2[5];
    #pragma unroll
    for (int kp = 0; kp < 5; kp++) {
        int kq = 2 * kp + tp; if (kq > 8) kq = 8;   // tap9 -> dummy (cwt zeroed)
        o2[kp] = op2[kq];
    }
    short8v a[5];
    #pragma unroll
    for (int kp = 0; kp < 5; kp++)
        a[kp] = wmf[((g * 5 + kp) * CGn + pr) * 4 + q];

    const ushort_t* xgb = (const ushort_t*)(ws + XGH_BASE)
                        + (size_t)(b * Gn + g) * XH_PIX * CGn;
    const unsigned hoff = (unsigned)half * 16u;

    #pragma unroll
    for (int kp = 0; kp < 5; kp++) {
        asm volatile("" : "+v"(o2[kp]));
        asm volatile("" : "+v"(a[kp]));
    }
    asm volatile("s_waitcnt vmcnt(0)" ::: "memory");
    __builtin_amdgcn_sched_barrier(0);

    float cwt[3][4];    // rotated: only 3 pairs live at once
    f32x4 dat[3][4];

#define PAIRSETUP(KP)                                                      \
  {                                                                        \
    const int k  = 2 * (KP) + tp;                                          \
    const int ki = k / 3, kj = k - 3 * ki;                                 \
    const float m = (k <= 8) ? 1.f : 0.f;                                  \
    const float ysf = (float)(ho - 1 + ki) + o2[KP].x;                     \
    const float xsf = (float)(wo - 1 + kj) + o2[KP].y;                     \
    const float y0f = floorf(ysf), x0f = floorf(xsf);                      \
    const int   y0  = (int)y0f,    x0  = (int)x0f;                         \
    const float wy1 = ysf - y0f, wx1 = xsf - x0f;                          \
    const float wy0 = 1.f - wy1, wx0 = 1.f - wx1;                          \
    const bool vy0 = (y0 >= 0)  && (y0 < Hn);                              \
    const bool vy1 = (y0 >= -1) && (y0 < Hn - 1);                          \
    const bool vx0 = (x0 >= 0)  && (x0 < Wn);                              \
    const bool vx1 = (x0 >= -1) && (x0 < Wn - 1);                          \
    const int cy0 = min(max(y0,     0), Hn - 1);                           \
    const int cy1 = min(max(y0 + 1, 0), Hn - 1);                           \
    const int cx0 = min(max(x0,     0), Wn - 1);                           \
    const int cx1 = min(max(x0 + 1, 0), Wn - 1);                           \
    cwt[(KP)%3][0] = m * wy0 * wx0 * ((vy0 && vx0) ? 1.f : 0.f);           \
    cwt[(KP)%3][1] = m * wy0 * wx1 * ((vy0 && vx1) ? 1.f : 0.f);           \
    cwt[(KP)%3][2] = m * wy1 * wx0 * ((vy1 && vx0) ? 1.f : 0.f);           \
    cwt[(KP)%3][3] = m * wy1 * wx1 * ((vy1 && vx1) ? 1.f : 0.f);           \
    const unsigned v00 = (unsigned)((cy0 + 1) * PW + cx0 + 1) * 32u + hoff; \
    const unsigned v01 = (unsigned)((cy0 + 1) * PW + cx1 + 1) * 32u + hoff; \
    const unsigned v10 = (unsigned)((cy1 + 1) * PW + cx0 + 1) * 32u + hoff; \
    const unsigned v11 = (unsigned)((cy1 + 1) * PW + cx1 + 1) * 32u + hoff; \
    GLOAD4(dat[(KP)%3][0], v00);                                           \
    GLOAD4(dat[(KP)%3][1], v01);                                           \
    GLOAD4(dat[(KP)%3][2], v10);                                           \
    GLOAD4(dat[(KP)%3][3], v11);                                           \
  }

    PAIRSETUP(0); PAIRSETUP(1); PAIRSETUP(2);

    f32x4 acc = {0.f, 0.f, 0.f, 0.f};

    #pragma unroll
    for (int kp = 0; kp < 5; kp++) {
        if (kp <= 2)      asm volatile("s_waitcnt vmcnt(8)" ::: "memory");
        else if (kp == 3) asm volatile("s_waitcnt vmcnt(4)" ::: "memory");
        else              asm volatile("s_waitcnt vmcnt(0)" ::: "memory");
        __builtin_amdgcn_sched_barrier(0);

        const int sl = kp % 3;
        float s[8] = {0.f,0.f,0.f,0.f,0.f,0.f,0.f,0.f};
        #pragma unroll
        for (int c4 = 0; c4 < 4; c4++) {
            const float w = cwt[sl][c4];
            const uint4v u = *reinterpret_cast<const uint4v*>(&dat[sl][c4]);
            #pragma unroll
            for (int w2 = 0; w2 < 4; w2++) {
                unsigned lo = u[w2] << 16;
                unsigned hi = u[w2] & 0xffff0000u;
                s[2*w2]   += w * *reinterpret_cast<float*>(&lo);
                s[2*w2+1] += w * *reinterpret_cast<float*>(&hi);
            }
        }
        short8v fr;
        #pragma unroll
        for (int j = 0; j < 8; j++) fr[j] = f2bs(s[j]);
        acc = __builtin_amdgcn_mfma_f32_16x16x32_bf16(a[kp], fr, acc, 0, 0, 0);

        // fence the combine before re-using the slot, then prefetch
        if (kp == 0) { __builtin_amdgcn_sched_barrier(0); PAIRSETUP(3); }
        if (kp == 1) { __builtin_amdgcn_sched_barrier(0); PAIRSETUP(4); }
    }

    float* op = out + (size_t)(b * Cn + g * CGn) * HWn + pos0;
    #pragma unroll
    for (int r = 0; r < 4; r++)
        op[(q * 4 + r) * HWn + pr] = acc[r];
}

// ---------------------------------------------------------------------------
extern "C" void kernel_launch(void* const* d_in, const int* in_sizes, int n_in,
                              void* d_out, int out_size, void* d_ws, size_t ws_size,
                              hipStream_t stream) {
    const float* x     = (const float*)d_in[0];
    const float* w_off = (const float*)d_in[1];
    const float* b_off = (const float*)d_in[2];
    const float* w_def = (const float*)d_in[3];
    float* out = (float*)d_out;
    float* ws  = (float*)d_ws;

    const int n_rest = 18432 + 10240 + NHALO;         // 34880
    const int nblk = NTRB + (n_rest + 255) / 256;     // 576 + 137
    prep_all<<<nblk, 256, 0, stream>>>(x, w_off, w_def, ws);

    offset_conv_v4<<<576, 256, 0, stream>>>(ws, b_off, ws + OFF_BASE);

    deform_v12<<<Bn * Gn * (HWn / 64), 256, 0, stream>>>(ws, out);
}

// Round 20
// 37.234 us; speedup vs baseline: 1.4569x; 1.0008x over previous
//
#include <hip/hip_runtime.h>
#include <hip/hip_bf16.h>

// Problem constants
#define Bn   4
#define Cn   64
#define Hn   96
#define Wn   96
#define Gn   4
#define CGn  16      // Cn / Gn
#define KKn  9
#define NOFF 18      // 2*K*K offset channels
#define HWn  (Hn*Wn) // 9216
#define PW   98      // padded width/height (1-px halo)
#define XH_PIX (PW*PW)   // 9604 pixels per plane
#define PLANE_B (XH_PIX * CGn * 2)   // 307328 bytes per (b,g) plane

// ws layout (floats)
#define OFF_BASE  0                        // B*HW*18 pos-major offsets (663552 fl)
#define AWF_BASE  (Bn*HWn*NOFF)            // offconv A-frags: 18432 bf16 = 9216 fl
#define WMF_BASE  (AWF_BASE + 9216)        // deform A-frags: 10240 bf16 = 5120 fl
#define XGH_BASE  (WMF_BASE + 5120)        // xgh[b][g][98*98][16] bf16 = 2458624 sh

typedef __attribute__((ext_vector_type(8))) short short8v;   // 8 bf16 = 4 VGPR
typedef __attribute__((ext_vector_type(4))) float f32x4;
typedef __attribute__((ext_vector_type(2))) float f32x2;
typedef __attribute__((ext_vector_type(4))) unsigned int uint4v;
typedef unsigned short ushort_t;

__device__ inline short f2bs(float v) {
    __hip_bfloat16 h = __float2bfloat16(v);
    return *reinterpret_cast<short*>(&h);
}
__device__ inline unsigned pack2bf(float lo, float hi) {
    return (unsigned)(ushort_t)f2bs(lo) | ((unsigned)(ushort_t)f2bs(hi) << 16);
}

// ---------------------------------------------------------------------------
// Kernel 0 (fused prep). Blocks [0,576): transpose x NCHW fp32 -> halo'd
// group-major bf16 image xgh[b][g][py*98+px][16]. Blocks [576,688): pack
// offconv + deform A-frags. Remaining: zero the halo of all 16 planes.
// ---------------------------------------------------------------------------
#define NTRB (Bn * (HWn / 64))   // 576 transpose blocks
#define NHALO (Bn * Gn * 388)    // 6208 halo pixels, 32 B each
__global__ __launch_bounds__(256) void prep_all(
    const float* __restrict__ x, const float* __restrict__ w_off,
    const float* __restrict__ w_def, float* __restrict__ ws)
{
    __shared__ float t[64][65];
    if (blockIdx.x < NTRB) {
        const int nb = HWn / 64;               // 144
        const int b  = blockIdx.x / nb;
        const int p0 = (blockIdx.x % nb) * 64;
        ushort_t* xgh = (ushort_t*)(ws + XGH_BASE);
        for (int i = threadIdx.x; i < 64 * 64; i += 256) {
            const int c = i >> 6, l = i & 63;
            t[c][l] = x[(b * Cn + c) * HWn + p0 + l];
        }
        __syncthreads();
        for (int i = threadIdx.x; i < 64 * 32; i += 256) {
            const int l = i >> 5, cp = i & 31;      // cp = channel pair
            const int pos = p0 + l;
            const int ho = pos / Wn, wo = pos % Wn;
            const unsigned pk = pack2bf(t[cp * 2][l], t[cp * 2 + 1][l]);
            const int g = cp >> 3, pg = cp & 7;     // group, pair-in-group
            *(unsigned*)(xgh + ((size_t)(b * Gn + g) * XH_PIX
                                + (ho + 1) * PW + (wo + 1)) * CGn + pg * 2) = pk;
        }
        return;
    }
    const int i = (blockIdx.x - NTRB) * 256 + threadIdx.x;
    const int NA = 18 * 2 * 16 * 4 * 8;    // 18432 offconv A-frag elems
    const int NW = Gn * 5 * CGn * 4 * 8;   // 10240 deform A-frag elems
    if (i < NA) {
        const int jj  = i & 7;
        const int q   = (i >> 3) & 3;
        const int row = (i >> 5) & 15;
        const int tt  = (i >> 9) & 1;
        const int s   = i >> 10;           // 0..17
        const int u   = s * 4 + q;
        const int k   = u % 9, co = u / 9;
        const int ci  = co * 8 + jj;
        const int o   = tt * 16 + row;
        const float v = (o < NOFF) ? w_off[(o * Cn + ci) * KKn + k] : 0.f;
        ((__hip_bfloat16*)(ws + AWF_BASE))[i] = __float2bfloat16(v);
    } else if (i < NA + NW) {
        const int j  = i - NA;
        const int jj = j & 7;
        const int q  = (j >> 3) & 3;
        const int d  = (j >> 5) & 15;
        const int kp = (j >> 9) % 5;
        const int g  = j / 2560;
        const int c  = (q & 1) * 8 + jj;
        const int k  = 2 * kp + (q >> 1);
        const float v = (k < KKn) ? w_def[((g * CGn + d) * CGn + c) * KKn + k] : 0.f;
        ((__hip_bfloat16*)(ws + WMF_BASE))[j] = __float2bfloat16(v);
    } else {
        const int hidx = i - (NA + NW);
        if (hidx < NHALO) {
            const int plane = hidx / 388;       // b*4+g
            const int h = hidx % 388;
            int py, px;
            if (h < 98)       { py = 0;           px = h;        }
            else if (h < 196) { py = 97;          px = h - 98;   }
            else if (h < 292) { py = h - 196 + 1; px = 0;        }
            else              { py = h - 292 + 1; px = 97;       }
            f32x4 z = {0.f, 0.f, 0.f, 0.f};
            f32x4* p = (f32x4*)((ushort_t*)(ws + XGH_BASE)
                       + ((size_t)plane * XH_PIX + py * PW + px) * CGn);
            p[0] = z; p[1] = z;
        }
    }
}

// ---------------------------------------------------------------------------
// Kernel 1: offset conv as MFMA GEMM on the halo'd group planes (no bounds
// checks). Wave = 16 pos. 18 kappa-steps; per step: one 16B B-load (8 bf16 ch
// = octet co&1 of group co>>1) + two A-frag loads; 2 MFMAs. Depth-6 pipeline.
// ---------------------------------------------------------------------------
__global__ __launch_bounds__(256) void offset_conv_v4(
    const float* __restrict__ ws, const float* __restrict__ bias,
    float* __restrict__ offs)
{
    // grid = 576 = 8 * 72 : XCD-swizzled
    const int bid = (blockIdx.x & 7) * 72 + (blockIdx.x >> 3);
    const int b = bid / 144;
    const int r = bid % 144;
    const int wave = threadIdx.x >> 6;
    const int lane = threadIdx.x & 63;
    const int pr = lane & 15, q = lane >> 4;
    const int pos0 = r * 64 + wave * 16;
    const int pos = pos0 + pr;
    const int ho = pos / Wn, wo = pos % Wn;
    const unsigned basep = (unsigned)(ho * PW + wo) * 32u;  // halo folds the +1s

    const ushort_t* xhb = (const ushort_t*)(ws + XGH_BASE)
                        + (size_t)b * Gn * XH_PIX * CGn;
    const ushort_t* awf = (const ushort_t*)(ws + AWF_BASE);
    const unsigned pa = (unsigned)(pr * 64 + q * 16);

    f32x4 bi4 = *(const f32x4*)(bias + q * 4);
    f32x2 bi2 = *(const f32x2*)(bias + 16);
    asm volatile("" : "+v"(bi4));
    asm volatile("" : "+v"(bi2));
    asm volatile("s_waitcnt vmcnt(0)" ::: "memory");
    __builtin_amdgcn_sched_barrier(0);

    short8v bfr[6], a0f[6], a1f[6];
    int kk = q, co = 0;          // invariant: u = s*4+q = 9*co + kk
    f32x4 acc0 = {0.f,0.f,0.f,0.f}, acc1 = {0.f,0.f,0.f,0.f};

#define OISSUE(S) { \
    const int ki = kk / 3, kj = kk % 3; \
    const unsigned voff = (unsigned)(co >> 1) * (unsigned)PLANE_B + basep \
                        + (unsigned)(ki * PW + kj) * 32u + (unsigned)(co & 1) * 16u; \
    asm volatile("global_load_dwordx4 %0, %1, %2" : "=v"(bfr[(S)%6]) : "v"(voff), "s"(xhb)); \
    const unsigned aoff = pa + (unsigned)(S) * 2048u; \
    asm volatile("global_load_dwordx4 %0, %1, %2" : "=v"(a0f[(S)%6]) : "v"(aoff), "s"(awf)); \
    asm volatile("global_load_dwordx4 %0, %1, %2" : "=v"(a1f[(S)%6]) : "v"(aoff + 1024u), "s"(awf)); \
    kk += 4; const int cy_ = (kk >= 9) ? 1 : 0; co += cy_; kk -= cy_ * 9; }

#define OCONS(S, N) { \
    asm volatile("s_waitcnt vmcnt(" #N ")" ::: "memory"); \
    __builtin_amdgcn_sched_barrier(0); \
    acc0 = __builtin_amdgcn_mfma_f32_16x16x32_bf16(a0f[(S)%6], bfr[(S)%6], acc0, 0, 0, 0); \
    acc1 = __builtin_amdgcn_mfma_f32_16x16x32_bf16(a1f[(S)%6], bfr[(S)%6], acc1, 0, 0, 0); }

    OISSUE(0) OISSUE(1) OISSUE(2) OISSUE(3) OISSUE(4) OISSUE(5)
    OCONS(0, 15) OISSUE(6)
    OCONS(1, 15) OISSUE(7)
    OCONS(2, 15) OISSUE(8)
    OCONS(3, 15) OISSUE(9)
    OCONS(4, 15) OISSUE(10)
    OCONS(5, 15) OISSUE(11)
    OCONS(6, 15) OISSUE(12)
    OCONS(7, 15) OISSUE(13)
    OCONS(8, 15) OISSUE(14)
    OCONS(9, 15) OISSUE(15)
    OCONS(10, 15) OISSUE(16)
    OCONS(11, 15) OISSUE(17)
    OCONS(12, 15)
    OCONS(13, 12)
    OCONS(14, 9)
    OCONS(15, 6)
    OCONS(16, 3)
    OCONS(17, 0)
#undef OISSUE
#undef OCONS

    float* dst = offs + (size_t)(b * HWn + pos0 + pr) * NOFF + q * 4;
    f32x2 s01; s01.x = acc0[0] + bi4.x; s01.y = acc0[1] + bi4.y;
    f32x2 s23; s23.x = acc0[2] + bi4.z; s23.y = acc0[3] + bi4.w;
    *(f32x2*)dst = s01;
    *(f32x2*)(dst + 2) = s23;
    if (q == 0) {
        f32x2 s67; s67.x = acc1[0] + bi2.x; s67.y = acc1[1] + bi2.y;
        *(f32x2*)(offs + (size_t)(b * HWn + pos0 + pr) * NOFF + 16) = s67;
    }
}

// ---------------------------------------------------------------------------
// Kernel 2: deformable conv via MFMA on the halo'd group plane (32B pixel
// lines). R8-proven v9 structure; dat/cwt rotated %3 (only 3 pairs live)
// to cut ~40 VGPR -> more resident waves. Counted vmcnt(8/8/8/4/0).
// ---------------------------------------------------------------------------
#define GLOAD4(dst, off_) \
    asm volatile("global_load_dwordx4 %0, %1, %2" \
                 : "=v"(dst) : "v"(off_), "s"(xgb))

__global__ __launch_bounds__(256) void deform_v12(
    const float* __restrict__ ws, float* __restrict__ out)
{
    const float* __restrict__ off2 = ws + OFF_BASE;
    const short8v* __restrict__ wmf = (const short8v*)(ws + WMF_BASE);

    // grid = 2304 = 8 * 288: XCD-swizzled
    const int bid = (blockIdx.x & 7) * 288 + (blockIdx.x >> 3);
    const int nbb = HWn / 64;              // 144 blocks per (b,g)
    const int bg  = bid / nbb;
    const int g   = bg & (Gn - 1);
    const int b   = bg >> 2;
    const int wave = threadIdx.x >> 6;
    const int lane = threadIdx.x & 63;
    const int pr   = lane & 15;
    const int q    = lane >> 4;
    const int half = q & 1;
    const int tp   = q >> 1;
    const int pos0 = (bid % nbb) * 64 + wave * 16;
    const int pos  = pos0 + pr;
    const int ho = pos / Wn, wo = pos % Wn;

    const f32x2* op2 = (const f32x2*)(off2 + (size_t)(b * HWn + pos) * NOFF);
    f32x2 o2[5];
    #pragma unroll
    for (int kp = 0; kp < 5; kp++) {
        int kq = 2 * kp + tp; if (kq > 8) kq = 8;   // tap9 -> dummy (cwt zeroed)
        o2[kp] = op2[kq];
    }
    short8v a[5];
    #pragma unroll
    for (int kp = 0; kp < 5; kp++)
        a[kp] = wmf[((g * 5 + kp) * CGn + pr) * 4 + q];

    const ushort_t* xgb = (const ushort_t*)(ws + XGH_BASE)
                        + (size_t)(b * Gn + g) * XH_PIX * CGn;
    const unsigned hoff = (unsigned)half * 16u;

    #pragma unroll
    for (int kp = 0; kp < 5; kp++) {
        asm volatile("" : "+v"(o2[kp]));
        asm volatile("" : "+v"(a[kp]));
    }
    asm volatile("s_waitcnt vmcnt(0)" ::: "memory");
    __builtin_amdgcn_sched_barrier(0);

    float cwt[3][4];    // rotated: only 3 pairs live at once
    f32x4 dat[3][4];

#define PAIRSETUP(KP)                                                      \
  {                                                                        \
    const int k  = 2 * (KP) + tp;                                          \
    const int ki = k / 3, kj = k - 3 * ki;                                 \
    const float m = (k <= 8) ? 1.f : 0.f;                                  \
    const float ysf = (float)(ho - 1 + ki) + o2[KP].x;                     \
    const float xsf = (float)(wo - 1 + kj) + o2[KP].y;                     \
    const float y0f = floorf(ysf), x0f = floorf(xsf);                      \
    const int   y0  = (int)y0f,    x0  = (int)x0f;                         \
    const float wy1 = ysf - y0f, wx1 = xsf - x0f;                          \
    const float wy0 = 1.f - wy1, wx0 = 1.f - wx1;                          \
    const bool vy0 = (y0 >= 0)  && (y0 < Hn);                              \
    const bool vy1 = (y0 >= -1) && (y0 < Hn - 1);                          \
    const bool vx0 = (x0 >= 0)  && (x0 < Wn);                              \
    const bool vx1 = (x0 >= -1) && (x0 < Wn - 1);                          \
    const int cy0 = min(max(y0,     0), Hn - 1);                           \
    const int cy1 = min(max(y0 + 1, 0), Hn - 1);                           \
    const int cx0 = min(max(x0,     0), Wn - 1);                           \
    const int cx1 = min(max(x0 + 1, 0), Wn - 1);                           \
    cwt[(KP)%3][0] = m * wy0 * wx0 * ((vy0 && vx0) ? 1.f : 0.f);           \
    cwt[(KP)%3][1] = m * wy0 * wx1 * ((vy0 && vx1) ? 1.f : 0.f);           \
    cwt[(KP)%3][2] = m * wy1 * wx0 * ((vy1 && vx0) ? 1.f : 0.f);           \
    cwt[(KP)%3][3] = m * wy1 * wx1 * ((vy1 && vx1) ? 1.f : 0.f);           \
    const unsigned v00 = (unsigned)((cy0 + 1) * PW + cx0 + 1) * 32u + hoff; \
    const unsigned v01 = (unsigned)((cy0 + 1) * PW + cx1 + 1) * 32u + hoff; \
    const unsigned v10 = (unsigned)((cy1 + 1) * PW + cx0 + 1) * 32u + hoff; \
    const unsigned v11 = (unsigned)((cy1 + 1) * PW + cx1 + 1) * 32u + hoff; \
    GLOAD4(dat[(KP)%3][0], v00);                                           \
    GLOAD4(dat[(KP)%3][1], v01);                                           \
    GLOAD4(dat[(KP)%3][2], v10);                                           \
    GLOAD4(dat[(KP)%3][3], v11);                                           \
  }

    PAIRSETUP(0); PAIRSETUP(1); PAIRSETUP(2);

    f32x4 acc = {0.f, 0.f, 0.f, 0.f};

    #pragma unroll
    for (int kp = 0; kp < 5; kp++) {
        if (kp <= 2)      asm volatile("s_waitcnt vmcnt(8)" ::: "memory");
        else if (kp == 3) asm volatile("s_waitcnt vmcnt(4)" ::: "memory");
        else              asm volatile("s_waitcnt vmcnt(0)" ::: "memory");
        __builtin_amdgcn_sched_barrier(0);

        const int sl = kp % 3;
        float s[8] = {0.f,0.f,0.f,0.f,0.f,0.f,0.f,0.f};
        #pragma unroll
        for (int c4 = 0; c4 < 4; c4++) {
            const float w = cwt[sl][c4];
            const uint4v u = *reinterpret_cast<const uint4v*>(&dat[sl][c4]);
            #pragma unroll
            for (int w2 = 0; w2 < 4; w2++) {
                unsigned lo = u[w2] << 16;
                unsigned hi = u[w2] & 0xffff0000u;
                s[2*w2]   += w * *reinterpret_cast<float*>(&lo);
                s[2*w2+1] += w * *reinterpret_cast<float*>(&hi);
            }
        }
        short8v fr;
        #pragma unroll
        for (int j = 0; j < 8; j++) fr[j] = f2bs(s[j]);
        acc = __builtin_amdgcn_mfma_f32_16x16x32_bf16(a[kp], fr, acc, 0, 0, 0);

        if (kp == 0) { __builtin_amdgcn_sched_barrier(0); PAIRSETUP(3); }
        if (kp == 1) { __builtin_amdgcn_sched_barrier(0); PAIRSETUP(4); }
    }

    float* op = out + (size_t)(b * Cn + g * CGn) * HWn + pos0;
    #pragma unroll
    for (int r = 0; r < 4; r++)
        op[(q * 4 + r) * HWn + pr] = acc[r];
}

// ---------------------------------------------------------------------------
extern "C" void kernel_launch(void* const* d_in, const int* in_sizes, int n_in,
                              void* d_out, int out_size, void* d_ws, size_t ws_size,
                              hipStream_t stream) {
    const float* x     = (const float*)d_in[0];
    const float* w_off = (const float*)d_in[1];
    const float* b_off = (const float*)d_in[2];
    const float* w_def = (const float*)d_in[3];
    float* out = (float*)d_out;
    float* ws  = (float*)d_ws;

    const int n_rest = 18432 + 10240 + NHALO;         // 34880
    const int nblk = NTRB + (n_rest + 255) / 256;     // 576 + 137
    prep_all<<<nblk, 256, 0, stream>>>(x, w_off, w_def, ws);

    offset_conv_v4<<<576, 256, 0, stream>>>(ws, b_off, ws + OFF_BASE);

    deform_v12<<<Bn * Gn * (HWn / 64), 256, 0, stream>>>(ws, out);
}